// Round 1
// baseline (124154.297 us; speedup 1.0000x reference)
//
#include <hip/hip_runtime.h>
#include <hip/hip_cooperative_groups.h>

namespace cg = cooperative_groups;

#define T_STEPS 4096
#define N_RES   2048
#define N_IN    64
#define N_OUT   64
#define LEAK    0.3f
#define NOISE_S 0.01f

// ---------------------------------------------------------------------------
// Kernel 1: it[t][n] = dot(u[t,:], W_in[n,:]) + 0.01*noise[t][n]
// one block per t, 256 threads; u[t] staged in LDS (broadcast reads).
// ---------------------------------------------------------------------------
__global__ __launch_bounds__(256) void input_terms_kernel(
    const float* __restrict__ u, const float* __restrict__ noise,
    const float* __restrict__ W_in, float* __restrict__ it) {
  const int t = blockIdx.x;
  const int tid = threadIdx.x;
  __shared__ float su[N_IN];
  if (tid < N_IN) su[tid] = u[(size_t)t * N_IN + tid];
  __syncthreads();
  #pragma unroll
  for (int k = 0; k < N_RES / 256; ++k) {
    const int n = tid + 256 * k;
    const float4* wr = reinterpret_cast<const float4*>(W_in + (size_t)n * N_IN);
    float acc = 0.f;
    #pragma unroll
    for (int j = 0; j < N_IN / 4; ++j) {
      float4 w4 = wr[j];
      acc = fmaf(w4.x, su[4 * j + 0], acc);
      acc = fmaf(w4.y, su[4 * j + 1], acc);
      acc = fmaf(w4.z, su[4 * j + 2], acc);
      acc = fmaf(w4.w, su[4 * j + 3], acc);
    }
    it[(size_t)t * N_RES + n] = acc + NOISE_S * noise[(size_t)t * N_RES + n];
  }
}

// ---------------------------------------------------------------------------
// Kernel 2: persistent cooperative recurrence.
// 256 WGs x 256 threads. WG w owns rows [8w, 8w+8). Wave v owns rows
// 8w+2v, 8w+2v+1. Lane l holds W[row][l + 64*j], j=0..31 in VGPRs.
// Double-buffered state (sbuf[0/1][2048]) in global ws -> 1 grid.sync/step.
// States are recorded by overwriting it[t][n] (consumed this step).
// ---------------------------------------------------------------------------
__global__ __launch_bounds__(256, 1) void reservoir_kernel(
    const float* __restrict__ W, float* __restrict__ it, float* sbuf) {
  const int wg = blockIdx.x;
  const int tid = threadIdx.x;
  const int wave = tid >> 6;
  const int lane = tid & 63;
  const int r0 = wg * 8 + wave * 2;  // this wave's two rows

  // Preload W rows into registers: 64 VGPRs/thread, read 16 MB once total.
  float w0[32], w1[32];
  #pragma unroll
  for (int j = 0; j < 32; ++j) {
    w0[j] = W[(size_t)r0 * N_RES + lane + 64 * j];
    w1[j] = W[(size_t)(r0 + 1) * N_RES + lane + 64 * j];
  }

  __shared__ float ls[N_RES];
  cg::grid_group grid = cg::this_grid();

  for (int t = 0; t < T_STEPS; ++t) {
    const float* sr = sbuf + (t & 1) * N_RES;
    float* sw = sbuf + ((t + 1) & 1) * N_RES;

    // Prefetch this wave's input terms early (hide global latency).
    float itv = 0.f;
    if (lane < 2) itv = it[(size_t)t * N_RES + r0 + lane];

    // Stage state to LDS. Agent-scope atomic loads bypass L1/L2 so
    // cross-XCD writes from the previous step are always visible.
    #pragma unroll
    for (int k = 0; k < N_RES / 256; ++k) {
      const int idx = tid + 256 * k;
      ls[idx] = __hip_atomic_load(sr + idx, __ATOMIC_RELAXED,
                                  __HIP_MEMORY_SCOPE_AGENT);
    }
    __syncthreads();

    // Two dot products per wave.
    float a0 = 0.f, a1 = 0.f;
    #pragma unroll
    for (int j = 0; j < 32; ++j) {
      const float s = ls[lane + 64 * j];
      a0 = fmaf(w0[j], s, a0);
      a1 = fmaf(w1[j], s, a1);
    }
    // Butterfly reduce across the 64-lane wave (all lanes get the sum).
    #pragma unroll
    for (int off = 32; off > 0; off >>= 1) {
      a0 += __shfl_xor(a0, off);
      a1 += __shfl_xor(a1, off);
    }

    if (lane < 2) {
      const float a = lane ? a1 : a0;
      const float h = tanhf(itv + a);
      const float sold = ls[r0 + lane];
      const float snew = (1.0f - LEAK) * sold + LEAK * h;
      __hip_atomic_store(sw + r0 + lane, snew, __ATOMIC_RELAXED,
                         __HIP_MEMORY_SCOPE_AGENT);
      it[(size_t)t * N_RES + r0 + lane] = snew;  // record state for readout
    }

    grid.sync();  // release writes, next step reads sw
  }
}

// ---------------------------------------------------------------------------
// Kernel 3: out[t][o] = dot(states[t,:], rw[o,:]) + rb[o]
// one block per t; 256 threads = 64 outputs x 4 partial slices.
// ---------------------------------------------------------------------------
__global__ __launch_bounds__(256) void readout_kernel(
    const float* __restrict__ states, const float* __restrict__ rw,
    const float* __restrict__ rb, float* __restrict__ out) {
  const int t = blockIdx.x;
  const int tid = threadIdx.x;
  const int o = tid & 63;
  const int q = tid >> 6;  // 0..3
  __shared__ float ss[N_RES];
  #pragma unroll
  for (int k = 0; k < N_RES / 256; ++k)
    ss[tid + 256 * k] = states[(size_t)t * N_RES + tid + 256 * k];
  __syncthreads();

  const float4* r4 = reinterpret_cast<const float4*>(rw + (size_t)o * N_RES + q * 512);
  float acc = 0.f;
  #pragma unroll 8
  for (int j = 0; j < 128; ++j) {
    float4 w4 = r4[j];
    const int base = q * 512 + 4 * j;
    acc = fmaf(w4.x, ss[base + 0], acc);
    acc = fmaf(w4.y, ss[base + 1], acc);
    acc = fmaf(w4.z, ss[base + 2], acc);
    acc = fmaf(w4.w, ss[base + 3], acc);
  }
  __shared__ float red[256];
  red[tid] = acc;
  __syncthreads();
  if (tid < 64) {
    float v = red[tid] + red[tid + 64] + red[tid + 128] + red[tid + 192];
    out[(size_t)t * N_OUT + tid] = v + rb[tid];
  }
}

// ---------------------------------------------------------------------------
extern "C" void kernel_launch(void* const* d_in, const int* in_sizes, int n_in,
                              void* d_out, int out_size, void* d_ws, size_t ws_size,
                              hipStream_t stream) {
  const float* u     = (const float*)d_in[0];  // [4096, 64]
  const float* noise = (const float*)d_in[1];  // [4096, 2048]
  const float* W_in  = (const float*)d_in[2];  // [2048, 64]
  const float* W     = (const float*)d_in[3];  // [2048, 2048]
  const float* rw    = (const float*)d_in[4];  // [64, 2048]
  const float* rb    = (const float*)d_in[5];  // [64]
  float* out = (float*)d_out;                  // [4096, 64]

  float* it   = (float*)d_ws;                                   // 32 MB (input terms -> states)
  float* sbuf = (float*)((char*)d_ws + (size_t)T_STEPS * N_RES * sizeof(float)); // 2*2048 f32

  // state double-buffer starts at zero (reset_state=True); ws is not
  // re-poisoned between replays, so zero it every call (deterministic).
  hipMemsetAsync(sbuf, 0, 2 * N_RES * sizeof(float), stream);

  input_terms_kernel<<<T_STEPS, 256, 0, stream>>>(u, noise, W_in, it);

  void* args[] = {(void*)&W, (void*)&it, (void*)&sbuf};
  hipLaunchCooperativeKernel((void*)reservoir_kernel, dim3(256), dim3(256),
                             args, 0, stream);

  readout_kernel<<<T_STEPS, 256, 0, stream>>>(it, rw, rb, out);
}